// Round 1
// 6252.561 us; speedup vs baseline: 1.2121x; 1.2121x over previous
//
#include <hip/hip_runtime.h>
#include <math.h>

#define HDIM 512
#define TPB  512              // 8 waves, 1 element per thread
#define NW   8                // waves per block
#define MIW  4                // M-tiles per wave (32 tiles / 8 waves)
#define SSTR 516              // LDS f32 row stride (512 + 4 pad)
#define NCH  22               // 1 value + 8 grads + 13 hessian pairs
#define NPR  13
#define NRED 57
#define LN_EPS 1e-5f

typedef _Float16 f16x8 __attribute__((ext_vector_type(8)));
typedef _Float16 f16x2 __attribute__((ext_vector_type(2)));
typedef float    f32x4 __attribute__((ext_vector_type(4)));

// Needed Hessian pairs (a<=b, b>=4): 26 total, split 13/13 across passes.
template<int P> struct PairSet;
template<> struct PairSet<0> {
    static constexpr int A[NPR] = {0,1,2,3,4, 0,1,2,3,4,5, 0,1};
    static constexpr int B[NPR] = {4,4,4,4,4, 5,5,5,5,5,5, 6,6};
};
template<> struct PairSet<1> {
    static constexpr int A[NPR] = {2,3,4,5,6, 0,1,2,3,4,5,6,7};
    static constexpr int B[NPR] = {6,6,6,6,6, 7,7,7,7,7,7,7,7};
};

// ---------- DPP wave-64 sum (VALU pipe, not DS). Result valid in lane 63. ----------
template<int CTRL>
__device__ __forceinline__ float dpp_add(float x) {
    int v = __builtin_amdgcn_update_dpp(0, __builtin_bit_cast(int, x),
                                        CTRL, 0xf, 0xf, true);
    return x + __builtin_bit_cast(float, v);
}
__device__ __forceinline__ float wave_sum_dpp(float x) {
    x = dpp_add<0x111>(x);   // row_shr:1
    x = dpp_add<0x112>(x);   // row_shr:2
    x = dpp_add<0x114>(x);   // row_shr:4
    x = dpp_add<0x118>(x);   // row_shr:8
    x = dpp_add<0x142>(x);   // row_bcast:15
    x = dpp_add<0x143>(x);   // row_bcast:31 -> lane63 = full wave sum
    return x;
}

// ---------- packed f32->f16 conversion helpers (v_cvt_pkrtz_f16_f32) ----------
__device__ __forceinline__ f16x8 pack_hi8(const float4 v0, const float4 v1) {
    union { f16x2 h[4]; f16x8 v8; } u;
    u.h[0] = __builtin_bit_cast(f16x2, __builtin_amdgcn_cvt_pkrtz(v0.x, v0.y));
    u.h[1] = __builtin_bit_cast(f16x2, __builtin_amdgcn_cvt_pkrtz(v0.z, v0.w));
    u.h[2] = __builtin_bit_cast(f16x2, __builtin_amdgcn_cvt_pkrtz(v1.x, v1.y));
    u.h[3] = __builtin_bit_cast(f16x2, __builtin_amdgcn_cvt_pkrtz(v1.z, v1.w));
    return u.v8;
}
__device__ __forceinline__ f16x8 pack_lo8(const float4 v0, const float4 v1, const f16x8 hi) {
    union { f16x2 h[4]; f16x8 v8; } u;
    u.h[0] = __builtin_bit_cast(f16x2, __builtin_amdgcn_cvt_pkrtz(
        (v0.x - (float)hi[0]) * 1024.f, (v0.y - (float)hi[1]) * 1024.f));
    u.h[1] = __builtin_bit_cast(f16x2, __builtin_amdgcn_cvt_pkrtz(
        (v0.z - (float)hi[2]) * 1024.f, (v0.w - (float)hi[3]) * 1024.f));
    u.h[2] = __builtin_bit_cast(f16x2, __builtin_amdgcn_cvt_pkrtz(
        (v1.x - (float)hi[4]) * 1024.f, (v1.y - (float)hi[5]) * 1024.f));
    u.h[3] = __builtin_bit_cast(f16x2, __builtin_amdgcn_cvt_pkrtz(
        (v1.z - (float)hi[6]) * 1024.f, (v1.w - (float)hi[7]) * 1024.f));
    return u.v8;
}

// ---------- prep: W1,W2 f32 -> hi/lo f16 in MFMA-fragment-contiguous layout ----------
__global__ void prep_kernel(const float* __restrict__ W1, const float* __restrict__ W2,
                            _Float16* __restrict__ ws) {
    const int gid  = blockIdx.x * 256 + threadIdx.x;
    const int layer = gid >> 18;
    const int r     = gid & 262143;
    const int i = r >> 9, j = r & 511;
    const float v = (layer ? W2 : W1)[r];
    const _Float16 hi = (_Float16)v;
    const _Float16 lo = (_Float16)((v - (float)hi) * 1024.f);
    const int mt = i >> 4, m = i & 15, ks = j >> 5, q = (j >> 3) & 3, e = j & 7;
    const int off = (((mt * 16 + ks) * 4 + q) * 16 + m) * 8 + e;
    _Float16* base = ws + (size_t)layer * 524288;
    base[off] = hi;
    base[262144 + off] = lo;
}

// ---------- MFMA gemm: D[512, 22] = W * S, result staged back into S (ch-major) ----------
__device__ void gemm_mfma(float* __restrict__ S,
                          const _Float16* __restrict__ Whi,
                          const _Float16* __restrict__ Wlo,
                          int w, int lane)
{
    const int q = lane >> 4, m = lane & 15;
    const int ch0 = m;
    const int ch1 = (16 + m < NCH) ? (16 + m) : (NCH - 1);  // clamp garbage lanes
    f32x4 acc[MIW][2];
    #pragma unroll
    for (int mi = 0; mi < MIW; ++mi) {
        acc[mi][0] = (f32x4){0.f, 0.f, 0.f, 0.f};
        acc[mi][1] = (f32x4){0.f, 0.f, 0.f, 0.f};
    }

    // ---- sweep A: cross terms Whi*Slo + Wlo*Shi ----
    #pragma unroll 1
    for (int ks = 0; ks < 16; ++ks) {
        f16x8 Bhi[2], Blo[2];
        #pragma unroll
        for (int nt = 0; nt < 2; ++nt) {
            const int ch = nt ? ch1 : ch0;
            const float* sp = S + ch * SSTR + ks * 32 + q * 8;
            const float4 v0 = *(const float4*)sp;
            const float4 v1 = *(const float4*)(sp + 4);
            Bhi[nt] = pack_hi8(v0, v1);
            Blo[nt] = pack_lo8(v0, v1, Bhi[nt]);
        }
        #pragma unroll
        for (int mi = 0; mi < MIW; ++mi) {
            const size_t fo = ((size_t)((w * MIW + mi) * 16 + ks) * 64 + lane) * 8;
            const f16x8 Ahi = *(const f16x8*)(Whi + fo);
            const f16x8 Alo = *(const f16x8*)(Wlo + fo);
            acc[mi][0] = __builtin_amdgcn_mfma_f32_16x16x32_f16(Ahi, Blo[0], acc[mi][0], 0, 0, 0);
            acc[mi][0] = __builtin_amdgcn_mfma_f32_16x16x32_f16(Alo, Bhi[0], acc[mi][0], 0, 0, 0);
            acc[mi][1] = __builtin_amdgcn_mfma_f32_16x16x32_f16(Ahi, Blo[1], acc[mi][1], 0, 0, 0);
            acc[mi][1] = __builtin_amdgcn_mfma_f32_16x16x32_f16(Alo, Bhi[1], acc[mi][1], 0, 0, 0);
        }
    }
    #pragma unroll
    for (int mi = 0; mi < MIW; ++mi) {
        acc[mi][0] *= (1.f / 1024.f);
        acc[mi][1] *= (1.f / 1024.f);
    }
    // ---- sweep B: main term Whi*Shi ----
    #pragma unroll 1
    for (int ks = 0; ks < 16; ++ks) {
        f16x8 Bhi[2];
        #pragma unroll
        for (int nt = 0; nt < 2; ++nt) {
            const int ch = nt ? ch1 : ch0;
            const float* sp = S + ch * SSTR + ks * 32 + q * 8;
            const float4 v0 = *(const float4*)sp;
            const float4 v1 = *(const float4*)(sp + 4);
            Bhi[nt] = pack_hi8(v0, v1);
        }
        #pragma unroll
        for (int mi = 0; mi < MIW; ++mi) {
            const size_t fo = ((size_t)((w * MIW + mi) * 16 + ks) * 64 + lane) * 8;
            const f16x8 Ahi = *(const f16x8*)(Whi + fo);
            acc[mi][0] = __builtin_amdgcn_mfma_f32_16x16x32_f16(Ahi, Bhi[0], acc[mi][0], 0, 0, 0);
            acc[mi][1] = __builtin_amdgcn_mfma_f32_16x16x32_f16(Ahi, Bhi[1], acc[mi][1], 0, 0, 0);
        }
    }

    __syncthreads();   // all waves done reading S -> safe to overwrite with D
    #pragma unroll
    for (int mi = 0; mi < MIW; ++mi) {
        #pragma unroll
        for (int nt = 0; nt < 2; ++nt) {
            const int ch = nt * 16 + m;
            if (ch < NCH) {
                const float4 st = {acc[mi][nt][0], acc[mi][nt][1], acc[mi][nt][2], acc[mi][nt][3]};
                *(float4*)(S + ch * SSTR + (w * MIW + mi) * 16 + q * 4) = st;
            }
        }
    }
    __syncthreads();
}

__device__ __forceinline__ void readback(float (&vals)[NCH],
                                         const float* __restrict__ b,
                                         const float* __restrict__ S, int tid)
{
    #pragma unroll
    for (int ch = 0; ch < NCH; ++ch) vals[ch] = S[ch * SSTR + tid];   // stride-1: conflict-free
    vals[0] += b[tid];
}

// ---------- softplus chain + LN; writes S (ch-major) or accumulates final linear ----------
// One element per thread. Wave-uniform derived stats live in LDS drv[] (broadcast reads),
// not per-thread registers.
template<int P, bool FINAL>
__device__ void ln_process(float (&vals)[NCH],
        const float* __restrict__ g, const float* __restrict__ be,
        float* __restrict__ S, float* __restrict__ red, float* __restrict__ fin,
        float* __restrict__ drv,
        float* __restrict__ sJ, float* __restrict__ sH,
        int tid, int lane, int w, float w3)
{
    const float pv  = vals[0];
    const float e   = expf(-fabsf(pv));
    const float sig = (pv >= 0.f) ? (1.f / (1.f + e)) : (e / (1.f + e));
    const float h   = fmaxf(pv, 0.f) + log1pf(e);
    const float spp = sig * (1.f - sig);
    #pragma unroll
    for (int t = 0; t < NPR; ++t) {
        const int a = PairSet<P>::A[t], b = PairSet<P>::B[t];
        vals[9+t] = sig * vals[9+t] + spp * vals[1+a] * vals[1+b];
    }
    #pragma unroll
    for (int a = 0; a < 8; ++a) vals[1+a] *= sig;
    vals[0] = h;

    // --- reduction group 1: k = 0..28 (registers die at the red[] store) ---
    {
        float pa[29];
        pa[0] = h;
        pa[1] = h * h;
        #pragma unroll
        for (int a = 0; a < 8; ++a) { pa[2+a] = vals[1+a]; pa[10+a] = h * vals[1+a]; }
        #pragma unroll
        for (int t = 0; t < 11; ++t) pa[18+t] = vals[9+t];
        #pragma unroll
        for (int k = 0; k < 29; ++k) pa[k] = wave_sum_dpp(pa[k]);
        if (lane == 63) {
            #pragma unroll
            for (int k = 0; k < 29; ++k) red[w * NRED + k] = pa[k];
        }
    }
    // --- reduction group 2: k = 29..56 ---
    {
        float pb[28];
        pb[0] = vals[9+11];
        pb[1] = vals[9+12];
        #pragma unroll
        for (int t = 0; t < NPR; ++t) {
            const int a = PairSet<P>::A[t], b = PairSet<P>::B[t];
            pb[2+t]  = vals[1+a] * vals[1+b];
            pb[15+t] = h * vals[9+t];
        }
        #pragma unroll
        for (int k = 0; k < 28; ++k) pb[k] = wave_sum_dpp(pb[k]);
        if (lane == 63) {
            #pragma unroll
            for (int k = 0; k < 28; ++k) red[w * NRED + 29 + k] = pb[k];
        }
    }
    __syncthreads();
    if (tid < NRED) {
        fin[tid] = ((red[tid] + red[NRED + tid]) + (red[2*NRED + tid] + red[3*NRED + tid]))
                 + ((red[4*NRED + tid] + red[5*NRED + tid]) + (red[6*NRED + tid] + red[7*NRED + tid]));
    }
    __syncthreads();

    const float invH = 1.f / HDIM;
    // derived stats -> drv[] : [0]=mean [1]=rs [2..9]=mdot [10..17]=sdot [18..30]=mdd [31..43]=cy
    if (tid < 8) {
        const float mean = fin[0] * invH;
        const float var  = fin[1] * invH - mean * mean;
        const float rs   = rsqrtf(var + LN_EPS);
        if (tid == 0) { drv[0] = mean; drv[1] = rs; }
        const float md = fin[2+tid] * invH;
        drv[2+tid]  = md;
        drv[10+tid] = (fin[10+tid] * invH - mean * md) * rs;
    }
    __syncthreads();
    if (tid < NPR) {
        const float mean = drv[0], rs = drv[1];
        const int a = PairSet<P>::A[tid], b = PairSet<P>::B[tid];
        const float sda = drv[10+a], sdb = drv[10+b];
        const float mdd = fin[18+tid] * invH;
        const float mcc = fin[31+tid] * invH - drv[2+a] * drv[2+b];
        const float mch = fin[44+tid] * invH - mean * mdd;
        const float vdd = 2.f * (mcc + mch);
        const float sdd = (0.5f * vdd - sda * sdb) * rs;
        drv[18+tid] = mdd;
        drv[31+tid] = 2.f * sda * sdb * rs * rs - sdd * rs;
    }
    __syncthreads();

    const float mean = drv[0], rs = drv[1];

    if (!FINAL) {
        const int j = tid;
        const float gi = g[j], bi = be[j];
        const float y = (vals[0] - mean) * rs;
        S[0 * SSTR + j] = y * gi + bi;
        float cd[8];
        #pragma unroll
        for (int a = 0; a < 8; ++a) {
            cd[a] = vals[1+a] - drv[2+a];
            S[(1+a) * SSTR + j] = (cd[a] - y * drv[10+a]) * rs * gi;
        }
        #pragma unroll
        for (int t = 0; t < NPR; ++t) {
            const int a = PairSet<P>::A[t], b = PairSet<P>::B[t];
            const float cdd = vals[9+t] - drv[18+t];
            const float ydd = cdd * rs - (cd[a]*drv[10+b] + cd[b]*drv[10+a]) * rs * rs
                              + y * drv[31+t];
            S[(9+t) * SSTR + j] = ydd * gi;
        }
    } else {
        float pf[NCH];
        const int j = tid;
        const float gi = g[j], bi = be[j];
        const float y = (vals[0] - mean) * rs;
        pf[0] = w3 * (y * gi + bi);
        float cd[8];
        #pragma unroll
        for (int a = 0; a < 8; ++a) {
            cd[a] = vals[1+a] - drv[2+a];
            pf[1+a] = w3 * ((cd[a] - y * drv[10+a]) * rs * gi);
        }
        #pragma unroll
        for (int t = 0; t < NPR; ++t) {
            const int a = PairSet<P>::A[t], b = PairSet<P>::B[t];
            const float cdd = vals[9+t] - drv[18+t];
            const float ydd = cdd * rs - (cd[a]*drv[10+b] + cd[b]*drv[10+a]) * rs * rs
                              + y * drv[31+t];
            pf[9+t] = w3 * (ydd * gi);
        }
        #pragma unroll
        for (int k = 0; k < NCH; ++k) pf[k] = wave_sum_dpp(pf[k]);
        if (lane == 63) {
            #pragma unroll
            for (int k = 0; k < NCH; ++k) red[w * NRED + k] = pf[k];
        }
        __syncthreads();
        if (tid < NCH) {
            fin[tid] = ((red[tid] + red[NRED + tid]) + (red[2*NRED + tid] + red[3*NRED + tid]))
                     + ((red[4*NRED + tid] + red[5*NRED + tid]) + (red[6*NRED + tid] + red[7*NRED + tid]));
        }
        __syncthreads();
        if (tid == 0) {
            if (P == 0) {
                #pragma unroll
                for (int a = 0; a < 8; ++a) sJ[a] = fin[1 + a];
            }
            #pragma unroll
            for (int t = 0; t < NPR; ++t) sH[P * NPR + t] = fin[9 + t];
        }
    }
}

template<int P>
__device__ void run_pass(int tid, int lane, int w, const float (&q)[8],
        const float* __restrict__ W0, const float* __restrict__ b0,
        const float* __restrict__ g0, const float* __restrict__ be0,
        const float* __restrict__ b1, const float* __restrict__ g1,
        const float* __restrict__ be1,
        const float* __restrict__ b2, const float* __restrict__ g2,
        const float* __restrict__ be2,
        const _Float16* __restrict__ Wf,
        float w3,
        float* S, float* red, float* fin, float* drv, float* sJ, float* sH)
{
    float vals[NCH];

    // ---- layer 0: q(8) -> 512 (no gemm); grads = W0 row, hess = 0
    {
        const float4 wa = *(const float4*)(W0 + tid * 8);
        const float4 wb = *(const float4*)(W0 + tid * 8 + 4);
        vals[0] = b0[tid]
            + wa.x*q[0] + wa.y*q[1] + wa.z*q[2] + wa.w*q[3]
            + wb.x*q[4] + wb.y*q[5] + wb.z*q[6] + wb.w*q[7];
        vals[1] = wa.x; vals[2] = wa.y; vals[3] = wa.z; vals[4] = wa.w;
        vals[5] = wb.x; vals[6] = wb.y; vals[7] = wb.z; vals[8] = wb.w;
        #pragma unroll
        for (int t = 0; t < NPR; ++t) vals[9+t] = 0.f;
    }
    ln_process<P, false>(vals, g0, be0, S, red, fin, drv, sJ, sH, tid, lane, w, w3);
    __syncthreads();

    // ---- layer 1
    gemm_mfma(S, Wf, Wf + 262144, w, lane);
    readback(vals, b1, S, tid);
    ln_process<P, false>(vals, g1, be1, S, red, fin, drv, sJ, sH, tid, lane, w, w3);
    __syncthreads();

    // ---- layer 2
    gemm_mfma(S, Wf + 524288, Wf + 786432, w, lane);
    readback(vals, b2, S, tid);
    ln_process<P, true>(vals, g2, be2, S, red, fin, drv, sJ, sH, tid, lane, w, w3);
    __syncthreads();
}

__global__ __launch_bounds__(TPB, 6)
void lnn_kernel(const float* __restrict__ x,
    const float* __restrict__ W0, const float* __restrict__ b0,
    const float* __restrict__ g0, const float* __restrict__ be0,
    const float* __restrict__ b1, const float* __restrict__ g1,
    const float* __restrict__ be1,
    const float* __restrict__ b2, const float* __restrict__ g2,
    const float* __restrict__ be2,
    const float* __restrict__ W3,
    const _Float16* __restrict__ Wf,
    float* __restrict__ out)
{
    __shared__ __align__(16) float S[NCH * SSTR];   // 45.4 KB: state / D-staging
    __shared__ __align__(16) float red[NW * NRED];
    __shared__ __align__(16) float fin[NRED + 3];
    __shared__ float drv[44];
    __shared__ float sJ[8];
    __shared__ float sH[26];

    const int tid  = threadIdx.x;
    const int lane = tid & 63;
    const int w    = tid >> 6;
    const long sample = blockIdx.x;

    float q[8];
    #pragma unroll
    for (int a = 0; a < 8; ++a) q[a] = x[sample * 8 + a];
    const float w3 = W3[tid];

    run_pass<0>(tid, lane, w, q, W0, b0, g0, be0, b1, g1, be1, b2, g2, be2,
                Wf, w3, S, red, fin, drv, sJ, sH);
    run_pass<1>(tid, lane, w, q, W0, b0, g0, be0, b1, g1, be1, b2, g2, be2,
                Wf, w3, S, red, fin, drv, sJ, sH);

    if (tid == 0) {
        const int off[4] = {0, 5, 11, 18};
        double Hd[26];
        for (int t = 0; t < 26; ++t) Hd[t] = (double)sH[t];
        double r[4];
        for (int k = 0; k < 4; ++k) {
            double s = (double)sJ[k];
            for (int j = 0; j < 4; ++j) s -= Hd[off[k] + j] * (double)q[4 + j];
            r[k] = s;
        }
        double A[4][5];
        for (int jj = 0; jj < 4; ++jj) {
            for (int k = 0; k < 4; ++k) {
                const int lo = (jj < k ? jj : k) + 4;
                const int hi = (jj < k ? k : jj) + 4;
                A[jj][k] = Hd[off[hi - 4] + lo];
            }
            A[jj][4] = r[jj];
        }
        for (int c = 0; c < 4; ++c) {
            int pr = c; double mx = fabs(A[c][c]);
            for (int rr = c + 1; rr < 4; ++rr)
                if (fabs(A[rr][c]) > mx) { mx = fabs(A[rr][c]); pr = rr; }
            if (pr != c)
                for (int cc = c; cc < 5; ++cc) {
                    double t = A[c][cc]; A[c][cc] = A[pr][cc]; A[pr][cc] = t;
                }
            const double pinv = 1.0 / A[c][c];
            for (int rr = 0; rr < 4; ++rr) if (rr != c) {
                const double f = A[rr][c] * pinv;
                for (int cc = c; cc < 5; ++cc) A[rr][cc] -= f * A[c][cc];
            }
        }
        #pragma unroll
        for (int k = 0; k < 4; ++k)
            out[sample * 4 + k] = (float)(A[k][4] / A[k][k]);
    }
}

extern "C" void kernel_launch(void* const* d_in, const int* in_sizes, int n_in,
                              void* d_out, int out_size, void* d_ws, size_t ws_size,
                              hipStream_t stream) {
    const float* x   = (const float*)d_in[0];
    const float* W0  = (const float*)d_in[1];
    const float* b0  = (const float*)d_in[2];
    const float* g0  = (const float*)d_in[3];
    const float* be0 = (const float*)d_in[4];
    const float* W1  = (const float*)d_in[5];
    const float* b1  = (const float*)d_in[6];
    const float* g1  = (const float*)d_in[7];
    const float* be1 = (const float*)d_in[8];
    const float* W2  = (const float*)d_in[9];
    const float* b2  = (const float*)d_in[10];
    const float* g2  = (const float*)d_in[11];
    const float* be2 = (const float*)d_in[12];
    const float* W3  = (const float*)d_in[13];
    float* out = (float*)d_out;

    _Float16* Wf = (_Float16*)d_ws;   // 2 MB: [W1hi|W1lo|W2hi|W2lo] fragment layout
    const int B = in_sizes[0] / 8;    // 16384

    hipLaunchKernelGGL(prep_kernel, dim3(2048), dim3(256), 0, stream, W1, W2, Wf);
    hipLaunchKernelGGL(lnn_kernel, dim3(B), dim3(TPB), 0, stream,
                       x, W0, b0, g0, be0, b1, g1, be1, b2, g2, be2, W3, Wf, out);
}

// Round 4
// 5377.242 us; speedup vs baseline: 1.4094x; 1.1628x over previous
//
#include <hip/hip_runtime.h>
#include <math.h>

#define HDIM 512
#define TPB  512              // 8 waves, 1 element per thread
#define NW   8                // waves per block
#define MIW  4                // M-tiles per wave (32 tiles / 8 waves)
#define SSTR 516              // LDS f32 row stride (512 + 4 pad)
#define NCH  22               // 1 value + 8 grads + 13 hessian pairs
#define NPR  13
#define NRED 57
#define LN_EPS 1e-5f

typedef _Float16 f16x8 __attribute__((ext_vector_type(8)));
typedef _Float16 f16x2 __attribute__((ext_vector_type(2)));
typedef float    f32x4 __attribute__((ext_vector_type(4)));

// Needed Hessian pairs (a<=b, b>=4): 26 total, split 13/13 across passes.
template<int P> struct PairSet;
template<> struct PairSet<0> {
    static constexpr int A[NPR] = {0,1,2,3,4, 0,1,2,3,4,5, 0,1};
    static constexpr int B[NPR] = {4,4,4,4,4, 5,5,5,5,5,5, 6,6};
};
template<> struct PairSet<1> {
    static constexpr int A[NPR] = {2,3,4,5,6, 0,1,2,3,4,5,6,7};
    static constexpr int B[NPR] = {6,6,6,6,6, 7,7,7,7,7,7,7,7};
};

// ---------- DPP wave-64 sum (VALU pipe). Result valid in lane 63. ----------
template<int CTRL>
__device__ __forceinline__ float dpp_add(float x) {
    int v = __builtin_amdgcn_update_dpp(0, __builtin_bit_cast(int, x),
                                        CTRL, 0xf, 0xf, true);
    return x + __builtin_bit_cast(float, v);
}
__device__ __forceinline__ float wave_sum_dpp(float x) {
    x = dpp_add<0x111>(x);   // row_shr:1
    x = dpp_add<0x112>(x);   // row_shr:2
    x = dpp_add<0x114>(x);   // row_shr:4
    x = dpp_add<0x118>(x);   // row_shr:8
    x = dpp_add<0x142>(x);   // row_bcast:15
    x = dpp_add<0x143>(x);   // row_bcast:31 -> lane63 = full wave sum
    return x;
}

// ---------- packed f32->f16 conversion helpers (v_cvt_pkrtz_f16_f32) ----------
__device__ __forceinline__ f16x8 pack_hi8(const float4 v0, const float4 v1) {
    union { f16x2 h[4]; f16x8 v8; } u;
    u.h[0] = __builtin_bit_cast(f16x2, __builtin_amdgcn_cvt_pkrtz(v0.x, v0.y));
    u.h[1] = __builtin_bit_cast(f16x2, __builtin_amdgcn_cvt_pkrtz(v0.z, v0.w));
    u.h[2] = __builtin_bit_cast(f16x2, __builtin_amdgcn_cvt_pkrtz(v1.x, v1.y));
    u.h[3] = __builtin_bit_cast(f16x2, __builtin_amdgcn_cvt_pkrtz(v1.z, v1.w));
    return u.v8;
}
__device__ __forceinline__ f16x8 pack_lo8(const float4 v0, const float4 v1, const f16x8 hi) {
    union { f16x2 h[4]; f16x8 v8; } u;
    u.h[0] = __builtin_bit_cast(f16x2, __builtin_amdgcn_cvt_pkrtz(
        (v0.x - (float)hi[0]) * 1024.f, (v0.y - (float)hi[1]) * 1024.f));
    u.h[1] = __builtin_bit_cast(f16x2, __builtin_amdgcn_cvt_pkrtz(
        (v0.z - (float)hi[2]) * 1024.f, (v0.w - (float)hi[3]) * 1024.f));
    u.h[2] = __builtin_bit_cast(f16x2, __builtin_amdgcn_cvt_pkrtz(
        (v1.x - (float)hi[4]) * 1024.f, (v1.y - (float)hi[5]) * 1024.f));
    u.h[3] = __builtin_bit_cast(f16x2, __builtin_amdgcn_cvt_pkrtz(
        (v1.z - (float)hi[6]) * 1024.f, (v1.w - (float)hi[7]) * 1024.f));
    return u.v8;
}

// ---------- prep: W1,W2 f32 -> hi/lo f16 in MFMA-fragment-contiguous layout ----------
__global__ void prep_kernel(const float* __restrict__ W1, const float* __restrict__ W2,
                            _Float16* __restrict__ ws) {
    const int gid  = blockIdx.x * 256 + threadIdx.x;
    const int layer = gid >> 18;
    const int r     = gid & 262143;
    const int i = r >> 9, j = r & 511;
    const float v = (layer ? W2 : W1)[r];
    const _Float16 hi = (_Float16)v;
    const _Float16 lo = (_Float16)((v - (float)hi) * 1024.f);
    const int mt = i >> 4, m = i & 15, ks = j >> 5, q = (j >> 3) & 3, e = j & 7;
    const int off = (((mt * 16 + ks) * 4 + q) * 16 + m) * 8 + e;
    _Float16* base = ws + (size_t)layer * 524288;
    base[off] = hi;
    base[262144 + off] = lo;
}

// ---------- MFMA gemm: D[512, 22] = W * S, result staged back into S (ch-major) ----------
__device__ void gemm_mfma(float* __restrict__ S,
                          const _Float16* __restrict__ Whi,
                          const _Float16* __restrict__ Wlo,
                          int w, int lane)
{
    const int q = lane >> 4, m = lane & 15;
    const int ch0 = m;
    const int ch1 = (16 + m < NCH) ? (16 + m) : (NCH - 1);  // clamp garbage lanes
    f32x4 acc[MIW][2];
    #pragma unroll
    for (int mi = 0; mi < MIW; ++mi) {
        acc[mi][0] = (f32x4){0.f, 0.f, 0.f, 0.f};
        acc[mi][1] = (f32x4){0.f, 0.f, 0.f, 0.f};
    }

    // ---- sweep A: cross terms Whi*Slo + Wlo*Shi ----
    #pragma unroll 1
    for (int ks = 0; ks < 16; ++ks) {
        f16x8 Bhi[2], Blo[2];
        #pragma unroll
        for (int nt = 0; nt < 2; ++nt) {
            const int ch = nt ? ch1 : ch0;
            const float* sp = S + ch * SSTR + ks * 32 + q * 8;
            const float4 v0 = *(const float4*)sp;
            const float4 v1 = *(const float4*)(sp + 4);
            Bhi[nt] = pack_hi8(v0, v1);
            Blo[nt] = pack_lo8(v0, v1, Bhi[nt]);
        }
        #pragma unroll
        for (int mi = 0; mi < MIW; ++mi) {
            const size_t fo = ((size_t)((w * MIW + mi) * 16 + ks) * 64 + lane) * 8;
            const f16x8 Ahi = *(const f16x8*)(Whi + fo);
            const f16x8 Alo = *(const f16x8*)(Wlo + fo);
            acc[mi][0] = __builtin_amdgcn_mfma_f32_16x16x32_f16(Ahi, Blo[0], acc[mi][0], 0, 0, 0);
            acc[mi][0] = __builtin_amdgcn_mfma_f32_16x16x32_f16(Alo, Bhi[0], acc[mi][0], 0, 0, 0);
            acc[mi][1] = __builtin_amdgcn_mfma_f32_16x16x32_f16(Ahi, Blo[1], acc[mi][1], 0, 0, 0);
            acc[mi][1] = __builtin_amdgcn_mfma_f32_16x16x32_f16(Alo, Bhi[1], acc[mi][1], 0, 0, 0);
        }
    }
    #pragma unroll
    for (int mi = 0; mi < MIW; ++mi) {
        acc[mi][0] *= (1.f / 1024.f);
        acc[mi][1] *= (1.f / 1024.f);
    }
    // ---- sweep B: main term Whi*Shi ----
    #pragma unroll 1
    for (int ks = 0; ks < 16; ++ks) {
        f16x8 Bhi[2];
        #pragma unroll
        for (int nt = 0; nt < 2; ++nt) {
            const int ch = nt ? ch1 : ch0;
            const float* sp = S + ch * SSTR + ks * 32 + q * 8;
            const float4 v0 = *(const float4*)sp;
            const float4 v1 = *(const float4*)(sp + 4);
            Bhi[nt] = pack_hi8(v0, v1);
        }
        #pragma unroll
        for (int mi = 0; mi < MIW; ++mi) {
            const size_t fo = ((size_t)((w * MIW + mi) * 16 + ks) * 64 + lane) * 8;
            const f16x8 Ahi = *(const f16x8*)(Whi + fo);
            acc[mi][0] = __builtin_amdgcn_mfma_f32_16x16x32_f16(Ahi, Bhi[0], acc[mi][0], 0, 0, 0);
            acc[mi][1] = __builtin_amdgcn_mfma_f32_16x16x32_f16(Ahi, Bhi[1], acc[mi][1], 0, 0, 0);
        }
    }

    __syncthreads();   // all waves done reading S -> safe to overwrite with D
    #pragma unroll
    for (int mi = 0; mi < MIW; ++mi) {
        #pragma unroll
        for (int nt = 0; nt < 2; ++nt) {
            const int ch = nt * 16 + m;
            if (ch < NCH) {
                const float4 st = {acc[mi][nt][0], acc[mi][nt][1], acc[mi][nt][2], acc[mi][nt][3]};
                *(float4*)(S + ch * SSTR + (w * MIW + mi) * 16 + q * 4) = st;
            }
        }
    }
    __syncthreads();
}

__device__ __forceinline__ void readback(float (&vals)[NCH],
                                         const float* __restrict__ b,
                                         const float* __restrict__ S, int tid)
{
    #pragma unroll
    for (int ch = 0; ch < NCH; ++ch) vals[ch] = S[ch * SSTR + tid];   // stride-1: conflict-free
    vals[0] += b[tid];
}

// ---------- softplus chain + LN; writes S (ch-major) or accumulates final linear ----------
// One element per thread. Wave-uniform derived stats live in LDS drv[] (broadcast reads),
// not per-thread registers.
template<int P, bool FINAL>
__device__ void ln_process(float (&vals)[NCH],
        const float* __restrict__ g, const float* __restrict__ be,
        float* __restrict__ S, float* __restrict__ red, float* __restrict__ fin,
        float* __restrict__ drv,
        float* __restrict__ sJ, float* __restrict__ sH,
        int tid, int lane, int w, float w3)
{
    const float pv  = vals[0];
    const float e   = expf(-fabsf(pv));
    const float sig = (pv >= 0.f) ? (1.f / (1.f + e)) : (e / (1.f + e));
    const float h   = fmaxf(pv, 0.f) + log1pf(e);
    const float spp = sig * (1.f - sig);
    #pragma unroll
    for (int t = 0; t < NPR; ++t) {
        const int a = PairSet<P>::A[t], b = PairSet<P>::B[t];
        vals[9+t] = sig * vals[9+t] + spp * vals[1+a] * vals[1+b];
    }
    #pragma unroll
    for (int a = 0; a < 8; ++a) vals[1+a] *= sig;
    vals[0] = h;

    // --- reduction group 1: k = 0..28 (registers die at the red[] store) ---
    {
        float pa[29];
        pa[0] = h;
        pa[1] = h * h;
        #pragma unroll
        for (int a = 0; a < 8; ++a) { pa[2+a] = vals[1+a]; pa[10+a] = h * vals[1+a]; }
        #pragma unroll
        for (int t = 0; t < 11; ++t) pa[18+t] = vals[9+t];
        #pragma unroll
        for (int k = 0; k < 29; ++k) pa[k] = wave_sum_dpp(pa[k]);
        if (lane == 63) {
            #pragma unroll
            for (int k = 0; k < 29; ++k) red[w * NRED + k] = pa[k];
        }
    }
    // --- reduction group 2: k = 29..56 ---
    {
        float pb[28];
        pb[0] = vals[9+11];
        pb[1] = vals[9+12];
        #pragma unroll
        for (int t = 0; t < NPR; ++t) {
            const int a = PairSet<P>::A[t], b = PairSet<P>::B[t];
            pb[2+t]  = vals[1+a] * vals[1+b];
            pb[15+t] = h * vals[9+t];
        }
        #pragma unroll
        for (int k = 0; k < 28; ++k) pb[k] = wave_sum_dpp(pb[k]);
        if (lane == 63) {
            #pragma unroll
            for (int k = 0; k < 28; ++k) red[w * NRED + 29 + k] = pb[k];
        }
    }
    __syncthreads();
    if (tid < NRED) {
        fin[tid] = ((red[tid] + red[NRED + tid]) + (red[2*NRED + tid] + red[3*NRED + tid]))
                 + ((red[4*NRED + tid] + red[5*NRED + tid]) + (red[6*NRED + tid] + red[7*NRED + tid]));
    }
    __syncthreads();

    const float invH = 1.f / HDIM;
    // derived stats -> drv[] : [0]=mean [1]=rs [2..9]=mdot [10..17]=sdot [18..30]=mdd [31..43]=cy
    if (tid < 8) {
        const float mean = fin[0] * invH;
        const float var  = fin[1] * invH - mean * mean;
        const float rs   = rsqrtf(var + LN_EPS);
        if (tid == 0) { drv[0] = mean; drv[1] = rs; }
        const float md = fin[2+tid] * invH;
        drv[2+tid]  = md;
        drv[10+tid] = (fin[10+tid] * invH - mean * md) * rs;
    }
    __syncthreads();
    if (tid < NPR) {
        const float mean = drv[0], rs = drv[1];
        const int a = PairSet<P>::A[tid], b = PairSet<P>::B[tid];
        const float sda = drv[10+a], sdb = drv[10+b];
        const float mdd = fin[18+tid] * invH;
        const float mcc = fin[31+tid] * invH - drv[2+a] * drv[2+b];
        const float mch = fin[44+tid] * invH - mean * mdd;
        const float vdd = 2.f * (mcc + mch);
        const float sdd = (0.5f * vdd - sda * sdb) * rs;
        drv[18+tid] = mdd;
        drv[31+tid] = 2.f * sda * sdb * rs * rs - sdd * rs;
    }
    __syncthreads();

    const float mean = drv[0], rs = drv[1];

    if (!FINAL) {
        const int j = tid;
        const float gi = g[j], bi = be[j];
        const float y = (vals[0] - mean) * rs;
        S[0 * SSTR + j] = y * gi + bi;
        float cd[8];
        #pragma unroll
        for (int a = 0; a < 8; ++a) {
            cd[a] = vals[1+a] - drv[2+a];
            S[(1+a) * SSTR + j] = (cd[a] - y * drv[10+a]) * rs * gi;
        }
        #pragma unroll
        for (int t = 0; t < NPR; ++t) {
            const int a = PairSet<P>::A[t], b = PairSet<P>::B[t];
            const float cdd = vals[9+t] - drv[18+t];
            const float ydd = cdd * rs - (cd[a]*drv[10+b] + cd[b]*drv[10+a]) * rs * rs
                              + y * drv[31+t];
            S[(9+t) * SSTR + j] = ydd * gi;
        }
    } else {
        float pf[NCH];
        const int j = tid;
        const float gi = g[j], bi = be[j];
        const float y = (vals[0] - mean) * rs;
        pf[0] = w3 * (y * gi + bi);
        float cd[8];
        #pragma unroll
        for (int a = 0; a < 8; ++a) {
            cd[a] = vals[1+a] - drv[2+a];
            pf[1+a] = w3 * ((cd[a] - y * drv[10+a]) * rs * gi);
        }
        #pragma unroll
        for (int t = 0; t < NPR; ++t) {
            const int a = PairSet<P>::A[t], b = PairSet<P>::B[t];
            const float cdd = vals[9+t] - drv[18+t];
            const float ydd = cdd * rs - (cd[a]*drv[10+b] + cd[b]*drv[10+a]) * rs * rs
                              + y * drv[31+t];
            pf[9+t] = w3 * (ydd * gi);
        }
        #pragma unroll
        for (int k = 0; k < NCH; ++k) pf[k] = wave_sum_dpp(pf[k]);
        if (lane == 63) {
            #pragma unroll
            for (int k = 0; k < NCH; ++k) red[w * NRED + k] = pf[k];
        }
        __syncthreads();
        if (tid < NCH) {
            fin[tid] = ((red[tid] + red[NRED + tid]) + (red[2*NRED + tid] + red[3*NRED + tid]))
                     + ((red[4*NRED + tid] + red[5*NRED + tid]) + (red[6*NRED + tid] + red[7*NRED + tid]));
        }
        __syncthreads();
        if (tid == 0) {
            if (P == 0) {
                #pragma unroll
                for (int a = 0; a < 8; ++a) sJ[a] = fin[1 + a];
            }
            #pragma unroll
            for (int t = 0; t < NPR; ++t) sH[P * NPR + t] = fin[9 + t];
        }
    }
}

template<int P>
__device__ void run_pass(int tid, int lane, int w, const float (&q)[8],
        const float* __restrict__ W0, const float* __restrict__ b0,
        const float* __restrict__ g0, const float* __restrict__ be0,
        const float* __restrict__ b1, const float* __restrict__ g1,
        const float* __restrict__ be1,
        const float* __restrict__ b2, const float* __restrict__ g2,
        const float* __restrict__ be2,
        const _Float16* __restrict__ Wf,
        float w3,
        float* S, float* red, float* fin, float* drv, float* sJ, float* sH)
{
    float vals[NCH];

    // ---- layer 0: q(8) -> 512 (no gemm); grads = W0 row, hess = 0
    {
        const float4 wa = *(const float4*)(W0 + tid * 8);
        const float4 wb = *(const float4*)(W0 + tid * 8 + 4);
        vals[0] = b0[tid]
            + wa.x*q[0] + wa.y*q[1] + wa.z*q[2] + wa.w*q[3]
            + wb.x*q[4] + wb.y*q[5] + wb.z*q[6] + wb.w*q[7];
        vals[1] = wa.x; vals[2] = wa.y; vals[3] = wa.z; vals[4] = wa.w;
        vals[5] = wb.x; vals[6] = wb.y; vals[7] = wb.z; vals[8] = wb.w;
        #pragma unroll
        for (int t = 0; t < NPR; ++t) vals[9+t] = 0.f;
    }
    ln_process<P, false>(vals, g0, be0, S, red, fin, drv, sJ, sH, tid, lane, w, w3);
    __syncthreads();

    // ---- layer 1
    gemm_mfma(S, Wf, Wf + 262144, w, lane);
    readback(vals, b1, S, tid);
    ln_process<P, false>(vals, g1, be1, S, red, fin, drv, sJ, sH, tid, lane, w, w3);
    __syncthreads();

    // ---- layer 2
    gemm_mfma(S, Wf + 524288, Wf + 786432, w, lane);
    readback(vals, b2, S, tid);
    ln_process<P, true>(vals, g2, be2, S, red, fin, drv, sJ, sH, tid, lane, w, w3);
    __syncthreads();
}

// block=512: LDS 48KB (<=64KB harness-safe). (512,4): 128-VGPR cap -> no scratch
// spills (round-1's (512,6)=85-cap spilled ~600B/thread -> 5.3GB scratch writes).
__global__ __launch_bounds__(TPB, 4)
void lnn_kernel(const float* __restrict__ x,
    const float* __restrict__ W0, const float* __restrict__ b0,
    const float* __restrict__ g0, const float* __restrict__ be0,
    const float* __restrict__ b1, const float* __restrict__ g1,
    const float* __restrict__ be1,
    const float* __restrict__ b2, const float* __restrict__ g2,
    const float* __restrict__ be2,
    const float* __restrict__ W3,
    const _Float16* __restrict__ Wf,
    float* __restrict__ out)
{
    __shared__ __align__(16) float S[NCH * SSTR];   // 45.4 KB: state / D-staging
    __shared__ __align__(16) float red[NW * NRED];
    __shared__ __align__(16) float fin[NRED + 3];
    __shared__ float drv[44];
    __shared__ float sJ[8];
    __shared__ float sH[26];

    const int tid  = threadIdx.x;
    const int lane = tid & 63;
    const int w    = tid >> 6;
    const long sample = blockIdx.x;

    float q[8];
    #pragma unroll
    for (int a = 0; a < 8; ++a) q[a] = x[sample * 8 + a];
    const float w3 = W3[tid];

    run_pass<0>(tid, lane, w, q, W0, b0, g0, be0, b1, g1, be1, b2, g2, be2,
                Wf, w3, S, red, fin, drv, sJ, sH);
    run_pass<1>(tid, lane, w, q, W0, b0, g0, be0, b1, g1, be1, b2, g2, be2,
                Wf, w3, S, red, fin, drv, sJ, sH);

    if (tid == 0) {
        const int off[4] = {0, 5, 11, 18};
        double Hd[26];
        for (int t = 0; t < 26; ++t) Hd[t] = (double)sH[t];
        double r[4];
        for (int k = 0; k < 4; ++k) {
            double s = (double)sJ[k];
            for (int j = 0; j < 4; ++j) s -= Hd[off[k] + j] * (double)q[4 + j];
            r[k] = s;
        }
        double A[4][5];
        for (int jj = 0; jj < 4; ++jj) {
            for (int k = 0; k < 4; ++k) {
                const int lo = (jj < k ? jj : k) + 4;
                const int hi = (jj < k ? k : jj) + 4;
                A[jj][k] = Hd[off[hi - 4] + lo];
            }
            A[jj][4] = r[jj];
        }
        for (int c = 0; c < 4; ++c) {
            int pr = c; double mx = fabs(A[c][c]);
            for (int rr = c + 1; rr < 4; ++rr)
                if (fabs(A[rr][c]) > mx) { mx = fabs(A[rr][c]); pr = rr; }
            if (pr != c)
                for (int cc = c; cc < 5; ++cc) {
                    double t = A[c][cc]; A[c][cc] = A[pr][cc]; A[pr][cc] = t;
                }
            const double pinv = 1.0 / A[c][c];
            for (int rr = 0; rr < 4; ++rr) if (rr != c) {
                const double f = A[rr][c] * pinv;
                for (int cc = c; cc < 5; ++cc) A[rr][cc] -= f * A[c][cc];
            }
        }
        #pragma unroll
        for (int k = 0; k < 4; ++k)
            out[sample * 4 + k] = (float)(A[k][4] / A[k][k]);
    }
}

extern "C" void kernel_launch(void* const* d_in, const int* in_sizes, int n_in,
                              void* d_out, int out_size, void* d_ws, size_t ws_size,
                              hipStream_t stream) {
    const float* x   = (const float*)d_in[0];
    const float* W0  = (const float*)d_in[1];
    const float* b0  = (const float*)d_in[2];
    const float* g0  = (const float*)d_in[3];
    const float* be0 = (const float*)d_in[4];
    const float* W1  = (const float*)d_in[5];
    const float* b1  = (const float*)d_in[6];
    const float* g1  = (const float*)d_in[7];
    const float* be1 = (const float*)d_in[8];
    const float* W2  = (const float*)d_in[9];
    const float* b2  = (const float*)d_in[10];
    const float* g2  = (const float*)d_in[11];
    const float* be2 = (const float*)d_in[12];
    const float* W3  = (const float*)d_in[13];
    float* out = (float*)d_out;

    _Float16* Wf = (_Float16*)d_ws;   // 2 MB: [W1hi|W1lo|W2hi|W2lo] fragment layout
    const int B = in_sizes[0] / 8;    // 16384

    hipLaunchKernelGGL(prep_kernel, dim3(2048), dim3(256), 0, stream, W1, W2, Wf);
    hipLaunchKernelGGL(lnn_kernel, dim3(B), dim3(TPB), 0, stream,
                       x, W0, b0, g0, be0, b1, g1, be1, b2, g2, be2, W3, Wf, out);
}

// Round 6
// 4964.394 us; speedup vs baseline: 1.5266x; 1.0832x over previous
//
#include <hip/hip_runtime.h>
#include <math.h>

#define HDIM 512
#define TPB  512              // 8 waves, 1 element per thread
#define NW   8                // waves per block
#define MIW  4                // M-tiles per wave (32 tiles / 8 waves)
#define SSTR 516              // LDS dword row stride (512 + 4 pad)
#define NCH  22               // 1 value + 8 grads + 13 hessian pairs
#define NPR  13
#define NRED 57
#define LN_EPS 1e-5f

typedef _Float16 f16x8 __attribute__((ext_vector_type(8)));
typedef _Float16 f16x2 __attribute__((ext_vector_type(2)));
typedef float    f32x4 __attribute__((ext_vector_type(4)));
typedef unsigned int uint32;

// Needed Hessian pairs (a<=b, b>=4): 26 total, split 13/13 across passes.
template<int P> struct PairSet;
template<> struct PairSet<0> {
    static constexpr int A[NPR] = {0,1,2,3,4, 0,1,2,3,4,5, 0,1};
    static constexpr int B[NPR] = {4,4,4,4,4, 5,5,5,5,5,5, 6,6};
};
template<> struct PairSet<1> {
    static constexpr int A[NPR] = {2,3,4,5,6, 0,1,2,3,4,5,6,7};
    static constexpr int B[NPR] = {6,6,6,6,6, 7,7,7,7,7,7,7,7};
};

// ---------- DPP wave-64 sum (VALU pipe). Result valid in lane 63. ----------
template<int CTRL>
__device__ __forceinline__ float dpp_add(float x) {
    int v = __builtin_amdgcn_update_dpp(0, __builtin_bit_cast(int, x),
                                        CTRL, 0xf, 0xf, true);
    return x + __builtin_bit_cast(float, v);
}
__device__ __forceinline__ float wave_sum_dpp(float x) {
    x = dpp_add<0x111>(x);   // row_shr:1
    x = dpp_add<0x112>(x);   // row_shr:2
    x = dpp_add<0x114>(x);   // row_shr:4
    x = dpp_add<0x118>(x);   // row_shr:8
    x = dpp_add<0x142>(x);   // row_bcast:15
    x = dpp_add<0x143>(x);   // row_bcast:31 -> lane63 = full wave sum
    return x;
}

// ---------- f32 -> packed (hi f16 in bits 15:0 | lo f16 in bits 31:16) ----------
// rtz rounding via cvt_pkrtz; lo scaled by 1024. Bit-exact with the r4-green
// per-gemm pack_hi8/pack_lo8 split (cvt_pkrtz converts each input independently).
__device__ __forceinline__ uint32 pack_hilo(float v) {
    const uint32 hiu = __builtin_bit_cast(uint32, __builtin_amdgcn_cvt_pkrtz(v, 0.f));
    const float  hf  = (float)__builtin_bit_cast(f16x2, hiu)[0];
    const uint32 lou = __builtin_bit_cast(uint32, __builtin_amdgcn_cvt_pkrtz((v - hf) * 1024.f, 0.f));
    return __builtin_amdgcn_perm(lou, hiu, 0x05040100u);  // b0,b1=hi  b2,b3=lo
}

// ---------- prep: W1,W2 f32 -> hi/lo f16 in MFMA-fragment-contiguous layout ----------
__global__ void prep_kernel(const float* __restrict__ W1, const float* __restrict__ W2,
                            _Float16* __restrict__ ws) {
    const int gid  = blockIdx.x * 256 + threadIdx.x;
    const int layer = gid >> 18;
    const int r     = gid & 262143;
    const int i = r >> 9, j = r & 511;
    const float v = (layer ? W2 : W1)[r];
    const _Float16 hi = (_Float16)v;
    const _Float16 lo = (_Float16)((v - (float)hi) * 1024.f);
    const int mt = i >> 4, m = i & 15, ks = j >> 5, q = (j >> 3) & 3, e = j & 7;
    const int off = (((mt * 16 + ks) * 4 + q) * 16 + m) * 8 + e;
    _Float16* base = ws + (size_t)layer * 524288;
    base[off] = hi;
    base[262144 + off] = lo;
}

// ---------- B-fragment unpack: 8 packed words -> hi f16x8 (+ optionally lo) ----------
__device__ __forceinline__ f16x8 unpack_hi(const uint4 d0, const uint4 d1) {
    union { uint32 u[4]; f16x8 v; } uh;
    uh.u[0] = __builtin_amdgcn_perm(d0.y, d0.x, 0x05040100u);
    uh.u[1] = __builtin_amdgcn_perm(d0.w, d0.z, 0x05040100u);
    uh.u[2] = __builtin_amdgcn_perm(d1.y, d1.x, 0x05040100u);
    uh.u[3] = __builtin_amdgcn_perm(d1.w, d1.z, 0x05040100u);
    return uh.v;
}
__device__ __forceinline__ f16x8 unpack_lo(const uint4 d0, const uint4 d1) {
    union { uint32 u[4]; f16x8 v; } ul;
    ul.u[0] = __builtin_amdgcn_perm(d0.y, d0.x, 0x07060302u);
    ul.u[1] = __builtin_amdgcn_perm(d0.w, d0.z, 0x07060302u);
    ul.u[2] = __builtin_amdgcn_perm(d1.y, d1.x, 0x07060302u);
    ul.u[3] = __builtin_amdgcn_perm(d1.w, d1.z, 0x07060302u);
    return ul.v;
}

// ---------- MFMA gemm: D[512, 22] = W * S, result staged back into S (ch-major) ----------
// S rows hold packed (hi|lo) f16 pairs; B fragments via v_perm (no cvt chains).
// Same two-sweep structure as r4-green: sweep A cross terms, rescale, sweep B main.
__device__ void gemm_mfma(float* __restrict__ S,
                          const _Float16* __restrict__ Whi,
                          const _Float16* __restrict__ Wlo,
                          int w, int lane)
{
    const int q = lane >> 4, m = lane & 15;
    const int ch0 = m;
    const int ch1 = (16 + m < NCH) ? (16 + m) : (NCH - 1);  // clamp garbage lanes
    f32x4 acc[MIW][2];
    #pragma unroll
    for (int mi = 0; mi < MIW; ++mi) {
        acc[mi][0] = (f32x4){0.f, 0.f, 0.f, 0.f};
        acc[mi][1] = (f32x4){0.f, 0.f, 0.f, 0.f};
    }

    // ---- sweep A: cross terms Whi*Slo + Wlo*Shi ----
    #pragma unroll 1
    for (int ks = 0; ks < 16; ++ks) {
        f16x8 Bhi[2], Blo[2];
        #pragma unroll
        for (int nt = 0; nt < 2; ++nt) {
            const int ch = nt ? ch1 : ch0;
            const uint32* sp = (const uint32*)(S + ch * SSTR + ks * 32 + q * 8);
            const uint4 d0 = *(const uint4*)sp;
            const uint4 d1 = *(const uint4*)(sp + 4);
            Bhi[nt] = unpack_hi(d0, d1);
            Blo[nt] = unpack_lo(d0, d1);
        }
        #pragma unroll
        for (int mi = 0; mi < MIW; ++mi) {
            const size_t fo = ((size_t)((w * MIW + mi) * 16 + ks) * 64 + lane) * 8;
            const f16x8 Ahi = *(const f16x8*)(Whi + fo);
            const f16x8 Alo = *(const f16x8*)(Wlo + fo);
            acc[mi][0] = __builtin_amdgcn_mfma_f32_16x16x32_f16(Ahi, Blo[0], acc[mi][0], 0, 0, 0);
            acc[mi][0] = __builtin_amdgcn_mfma_f32_16x16x32_f16(Alo, Bhi[0], acc[mi][0], 0, 0, 0);
            acc[mi][1] = __builtin_amdgcn_mfma_f32_16x16x32_f16(Ahi, Blo[1], acc[mi][1], 0, 0, 0);
            acc[mi][1] = __builtin_amdgcn_mfma_f32_16x16x32_f16(Alo, Bhi[1], acc[mi][1], 0, 0, 0);
        }
    }
    #pragma unroll
    for (int mi = 0; mi < MIW; ++mi) {
        acc[mi][0] *= (1.f / 1024.f);
        acc[mi][1] *= (1.f / 1024.f);
    }
    // ---- sweep B: main term Whi*Shi ----
    #pragma unroll 1
    for (int ks = 0; ks < 16; ++ks) {
        f16x8 Bhi[2];
        #pragma unroll
        for (int nt = 0; nt < 2; ++nt) {
            const int ch = nt ? ch1 : ch0;
            const uint32* sp = (const uint32*)(S + ch * SSTR + ks * 32 + q * 8);
            const uint4 d0 = *(const uint4*)sp;
            const uint4 d1 = *(const uint4*)(sp + 4);
            Bhi[nt] = unpack_hi(d0, d1);
        }
        #pragma unroll
        for (int mi = 0; mi < MIW; ++mi) {
            const size_t fo = ((size_t)((w * MIW + mi) * 16 + ks) * 64 + lane) * 8;
            const f16x8 Ahi = *(const f16x8*)(Whi + fo);
            acc[mi][0] = __builtin_amdgcn_mfma_f32_16x16x32_f16(Ahi, Bhi[0], acc[mi][0], 0, 0, 0);
            acc[mi][1] = __builtin_amdgcn_mfma_f32_16x16x32_f16(Ahi, Bhi[1], acc[mi][1], 0, 0, 0);
        }
    }

    __syncthreads();   // all waves done reading S -> safe to overwrite with D (f32)
    #pragma unroll
    for (int mi = 0; mi < MIW; ++mi) {
        #pragma unroll
        for (int nt = 0; nt < 2; ++nt) {
            const int ch = nt * 16 + m;
            if (ch < NCH) {
                const float4 st = {acc[mi][nt][0], acc[mi][nt][1], acc[mi][nt][2], acc[mi][nt][3]};
                *(float4*)(S + ch * SSTR + (w * MIW + mi) * 16 + q * 4) = st;
            }
        }
    }
    __syncthreads();
}

__device__ __forceinline__ void readback(float (&vals)[NCH],
                                         const float* __restrict__ b,
                                         const float* __restrict__ S, int tid)
{
    #pragma unroll
    for (int ch = 0; ch < NCH; ++ch) vals[ch] = S[ch * SSTR + tid];   // f32 D, stride-1
    vals[0] += b[tid];
}

// ---------- softplus chain + LN; writes S (packed hi/lo) or accumulates final linear ----------
// Structure identical to the r4-green kernel except the S-writes pack hi/lo.
template<int P, bool FINAL>
__device__ void ln_process(float (&vals)[NCH],
        const float* __restrict__ g, const float* __restrict__ be,
        float* __restrict__ S, float* __restrict__ red, float* __restrict__ fin,
        float* __restrict__ drv,
        float* __restrict__ sJ, float* __restrict__ sH,
        int tid, int lane, int w, float w3)
{
    const float pv  = vals[0];
    const float e   = expf(-fabsf(pv));
    const float sig = (pv >= 0.f) ? (1.f / (1.f + e)) : (e / (1.f + e));
    const float h   = fmaxf(pv, 0.f) + log1pf(e);
    const float spp = sig * (1.f - sig);
    #pragma unroll
    for (int t = 0; t < NPR; ++t) {
        const int a = PairSet<P>::A[t], b = PairSet<P>::B[t];
        vals[9+t] = sig * vals[9+t] + spp * vals[1+a] * vals[1+b];
    }
    #pragma unroll
    for (int a = 0; a < 8; ++a) vals[1+a] *= sig;
    vals[0] = h;

    // --- reduction group 1: k = 0..28 (registers die at the red[] store) ---
    {
        float pa[29];
        pa[0] = h;
        pa[1] = h * h;
        #pragma unroll
        for (int a = 0; a < 8; ++a) { pa[2+a] = vals[1+a]; pa[10+a] = h * vals[1+a]; }
        #pragma unroll
        for (int t = 0; t < 11; ++t) pa[18+t] = vals[9+t];
        #pragma unroll
        for (int k = 0; k < 29; ++k) pa[k] = wave_sum_dpp(pa[k]);
        if (lane == 63) {
            #pragma unroll
            for (int k = 0; k < 29; ++k) red[w * NRED + k] = pa[k];
        }
    }
    // --- reduction group 2: k = 29..56 ---
    {
        float pb[28];
        pb[0] = vals[9+11];
        pb[1] = vals[9+12];
        #pragma unroll
        for (int t = 0; t < NPR; ++t) {
            const int a = PairSet<P>::A[t], b = PairSet<P>::B[t];
            pb[2+t]  = vals[1+a] * vals[1+b];
            pb[15+t] = h * vals[9+t];
        }
        #pragma unroll
        for (int k = 0; k < 28; ++k) pb[k] = wave_sum_dpp(pb[k]);
        if (lane == 63) {
            #pragma unroll
            for (int k = 0; k < 28; ++k) red[w * NRED + 29 + k] = pb[k];
        }
    }
    __syncthreads();
    if (tid < NRED) {
        fin[tid] = ((red[tid] + red[NRED + tid]) + (red[2*NRED + tid] + red[3*NRED + tid]))
                 + ((red[4*NRED + tid] + red[5*NRED + tid]) + (red[6*NRED + tid] + red[7*NRED + tid]));
    }
    __syncthreads();

    const float invH = 1.f / HDIM;
    // derived stats -> drv[] : [0]=mean [1]=rs [2..9]=mdot [10..17]=sdot [18..30]=mdd [31..43]=cy
    if (tid < 8) {
        const float mean = fin[0] * invH;
        const float var  = fin[1] * invH - mean * mean;
        const float rs   = rsqrtf(var + LN_EPS);
        if (tid == 0) { drv[0] = mean; drv[1] = rs; }
        const float md = fin[2+tid] * invH;
        drv[2+tid]  = md;
        drv[10+tid] = (fin[10+tid] * invH - mean * md) * rs;
    }
    __syncthreads();
    if (tid < NPR) {
        const float mean = drv[0], rs = drv[1];
        const int a = PairSet<P>::A[tid], b = PairSet<P>::B[tid];
        const float sda = drv[10+a], sdb = drv[10+b];
        const float mdd = fin[18+tid] * invH;
        const float mcc = fin[31+tid] * invH - drv[2+a] * drv[2+b];
        const float mch = fin[44+tid] * invH - mean * mdd;
        const float vdd = 2.f * (mcc + mch);
        const float sdd = (0.5f * vdd - sda * sdb) * rs;
        drv[18+tid] = mdd;
        drv[31+tid] = 2.f * sda * sdb * rs * rs - sdd * rs;
    }
    __syncthreads();

    const float mean = drv[0], rs = drv[1];

    if (!FINAL) {
        const int j = tid;
        const float gi = g[j], bi = be[j];
        const float y = (vals[0] - mean) * rs;
        uint32* Su = (uint32*)S;
        Su[0 * SSTR + j] = pack_hilo(y * gi + bi);
        float cd[8];
        #pragma unroll
        for (int a = 0; a < 8; ++a) {
            cd[a] = vals[1+a] - drv[2+a];
            Su[(1+a) * SSTR + j] = pack_hilo((cd[a] - y * drv[10+a]) * rs * gi);
        }
        #pragma unroll
        for (int t = 0; t < NPR; ++t) {
            const int a = PairSet<P>::A[t], b = PairSet<P>::B[t];
            const float cdd = vals[9+t] - drv[18+t];
            const float ydd = cdd * rs - (cd[a]*drv[10+b] + cd[b]*drv[10+a]) * rs * rs
                              + y * drv[31+t];
            Su[(9+t) * SSTR + j] = pack_hilo(ydd * gi);
        }
    } else {
        float pf[NCH];
        const int j = tid;
        const float gi = g[j], bi = be[j];
        const float y = (vals[0] - mean) * rs;
        pf[0] = w3 * (y * gi + bi);
        float cd[8];
        #pragma unroll
        for (int a = 0; a < 8; ++a) {
            cd[a] = vals[1+a] - drv[2+a];
            pf[1+a] = w3 * ((cd[a] - y * drv[10+a]) * rs * gi);
        }
        #pragma unroll
        for (int t = 0; t < NPR; ++t) {
            const int a = PairSet<P>::A[t], b = PairSet<P>::B[t];
            const float cdd = vals[9+t] - drv[18+t];
            const float ydd = cdd * rs - (cd[a]*drv[10+b] + cd[b]*drv[10+a]) * rs * rs
                              + y * drv[31+t];
            pf[9+t] = w3 * (ydd * gi);
        }
        #pragma unroll
        for (int k = 0; k < NCH; ++k) pf[k] = wave_sum_dpp(pf[k]);
        if (lane == 63) {
            #pragma unroll
            for (int k = 0; k < NCH; ++k) red[w * NRED + k] = pf[k];
        }
        __syncthreads();
        if (tid < NCH) {
            fin[tid] = ((red[tid] + red[NRED + tid]) + (red[2*NRED + tid] + red[3*NRED + tid]))
                     + ((red[4*NRED + tid] + red[5*NRED + tid]) + (red[6*NRED + tid] + red[7*NRED + tid]));
        }
        __syncthreads();
        if (tid == 0) {
            if (P == 0) {
                #pragma unroll
                for (int a = 0; a < 8; ++a) sJ[a] = fin[1 + a];
            }
            #pragma unroll
            for (int t = 0; t < NPR; ++t) sH[P * NPR + t] = fin[9 + t];
        }
    }
}

template<int P>
__device__ void run_pass(int tid, int lane, int w, const float (&q)[8],
        const float* __restrict__ W0, const float* __restrict__ b0,
        const float* __restrict__ g0, const float* __restrict__ be0,
        const float* __restrict__ b1, const float* __restrict__ g1,
        const float* __restrict__ be1,
        const float* __restrict__ b2, const float* __restrict__ g2,
        const float* __restrict__ be2,
        const _Float16* __restrict__ Wf,
        float w3,
        float* S, float* red, float* fin, float* drv, float* sJ, float* sH)
{
    float vals[NCH];

    // ---- layer 0: q(8) -> 512 (no gemm); grads = W0 row, hess = 0
    {
        const float4 wa = *(const float4*)(W0 + tid * 8);
        const float4 wb = *(const float4*)(W0 + tid * 8 + 4);
        vals[0] = b0[tid]
            + wa.x*q[0] + wa.y*q[1] + wa.z*q[2] + wa.w*q[3]
            + wb.x*q[4] + wb.y*q[5] + wb.z*q[6] + wb.w*q[7];
        vals[1] = wa.x; vals[2] = wa.y; vals[3] = wa.z; vals[4] = wa.w;
        vals[5] = wb.x; vals[6] = wb.y; vals[7] = wb.z; vals[8] = wb.w;
        #pragma unroll
        for (int t = 0; t < NPR; ++t) vals[9+t] = 0.f;
    }
    ln_process<P, false>(vals, g0, be0, S, red, fin, drv, sJ, sH, tid, lane, w, w3);
    __syncthreads();

    // ---- layer 1
    gemm_mfma(S, Wf, Wf + 262144, w, lane);
    readback(vals, b1, S, tid);
    ln_process<P, false>(vals, g1, be1, S, red, fin, drv, sJ, sH, tid, lane, w, w3);
    __syncthreads();

    // ---- layer 2
    gemm_mfma(S, Wf + 524288, Wf + 786432, w, lane);
    readback(vals, b2, S, tid);
    ln_process<P, true>(vals, g2, be2, S, red, fin, drv, sJ, sH, tid, lane, w, w3);
    __syncthreads();
}

// Bisect discipline: this kernel is the r4-green kernel + packed hi/lo S storage
// ONLY. Sync structure, LDS layout (48KB, no aliasing), reduction scheme, and
// launch bounds are byte-identical to the passing round-4 kernel.
__global__ __launch_bounds__(TPB, 4)
void lnn_kernel(const float* __restrict__ x,
    const float* __restrict__ W0, const float* __restrict__ b0,
    const float* __restrict__ g0, const float* __restrict__ be0,
    const float* __restrict__ b1, const float* __restrict__ g1,
    const float* __restrict__ be1,
    const float* __restrict__ b2, const float* __restrict__ g2,
    const float* __restrict__ be2,
    const float* __restrict__ W3,
    const _Float16* __restrict__ Wf,
    float* __restrict__ out)
{
    __shared__ __align__(16) float S[NCH * SSTR];   // 45.4 KB: state / D-staging
    __shared__ __align__(16) float red[NW * NRED];
    __shared__ __align__(16) float fin[NRED + 3];
    __shared__ float drv[44];
    __shared__ float sJ[8];
    __shared__ float sH[26];

    const int tid  = threadIdx.x;
    const int lane = tid & 63;
    const int w    = tid >> 6;
    const long sample = blockIdx.x;

    float q[8];
    #pragma unroll
    for (int a = 0; a < 8; ++a) q[a] = x[sample * 8 + a];
    const float w3 = W3[tid];

    run_pass<0>(tid, lane, w, q, W0, b0, g0, be0, b1, g1, be1, b2, g2, be2,
                Wf, w3, S, red, fin, drv, sJ, sH);
    run_pass<1>(tid, lane, w, q, W0, b0, g0, be0, b1, g1, be1, b2, g2, be2,
                Wf, w3, S, red, fin, drv, sJ, sH);

    if (tid == 0) {
        const int off[4] = {0, 5, 11, 18};
        double Hd[26];
        for (int t = 0; t < 26; ++t) Hd[t] = (double)sH[t];
        double r[4];
        for (int k = 0; k < 4; ++k) {
            double s = (double)sJ[k];
            for (int j = 0; j < 4; ++j) s -= Hd[off[k] + j] * (double)q[4 + j];
            r[k] = s;
        }
        double A[4][5];
        for (int jj = 0; jj < 4; ++jj) {
            for (int k = 0; k < 4; ++k) {
                const int lo = (jj < k ? jj : k) + 4;
                const int hi = (jj < k ? k : jj) + 4;
                A[jj][k] = Hd[off[hi - 4] + lo];
            }
            A[jj][4] = r[jj];
        }
        for (int c = 0; c < 4; ++c) {
            int pr = c; double mx = fabs(A[c][c]);
            for (int rr = c + 1; rr < 4; ++rr)
                if (fabs(A[rr][c]) > mx) { mx = fabs(A[rr][c]); pr = rr; }
            if (pr != c)
                for (int cc = c; cc < 5; ++cc) {
                    double t = A[c][cc]; A[c][cc] = A[pr][cc]; A[pr][cc] = t;
                }
            const double pinv = 1.0 / A[c][c];
            for (int rr = 0; rr < 4; ++rr) if (rr != c) {
                const double f = A[rr][c] * pinv;
                for (int cc = c; cc < 5; ++cc) A[rr][cc] -= f * A[c][cc];
            }
        }
        #pragma unroll
        for (int k = 0; k < 4; ++k)
            out[sample * 4 + k] = (float)(A[k][4] / A[k][k]);
    }
}

extern "C" void kernel_launch(void* const* d_in, const int* in_sizes, int n_in,
                              void* d_out, int out_size, void* d_ws, size_t ws_size,
                              hipStream_t stream) {
    const float* x   = (const float*)d_in[0];
    const float* W0  = (const float*)d_in[1];
    const float* b0  = (const float*)d_in[2];
    const float* g0  = (const float*)d_in[3];
    const float* be0 = (const float*)d_in[4];
    const float* W1  = (const float*)d_in[5];
    const float* b1  = (const float*)d_in[6];
    const float* g1  = (const float*)d_in[7];
    const float* be1 = (const float*)d_in[8];
    const float* W2  = (const float*)d_in[9];
    const float* b2  = (const float*)d_in[10];
    const float* g2  = (const float*)d_in[11];
    const float* be2 = (const float*)d_in[12];
    const float* W3  = (const float*)d_in[13];
    float* out = (float*)d_out;

    _Float16* Wf = (_Float16*)d_ws;   // 2 MB: [W1hi|W1lo|W2hi|W2lo] fragment layout
    const int B = in_sizes[0] / 8;    // 16384

    hipLaunchKernelGGL(prep_kernel, dim3(2048), dim3(256), 0, stream, W1, W2, Wf);
    hipLaunchKernelGGL(lnn_kernel, dim3(B), dim3(TPB), 0, stream,
                       x, W0, b0, g0, be0, b1, g1, be1, b2, g2, be2, W3, Wf, out);
}

// Round 7
// 4272.018 us; speedup vs baseline: 1.7741x; 1.1621x over previous
//
#include <hip/hip_runtime.h>
#include <math.h>

#define HDIM 512
#define TPB  512              // 8 waves, 1 element per thread
#define NW   8                // waves per block
#define MIW  4                // M-tiles per wave (32 tiles / 8 waves)
#define SSTR 516              // LDS dword row stride (512 + 4 pad)
#define NCH  22               // 1 value + 8 grads + 13 hessian pairs
#define NPR  13
#define NRED 57
#define LN_EPS 1e-5f

typedef _Float16 f16x8 __attribute__((ext_vector_type(8)));
typedef _Float16 f16x2 __attribute__((ext_vector_type(2)));
typedef float    f32x4 __attribute__((ext_vector_type(4)));
typedef unsigned int uint32;

// Needed Hessian pairs (a<=b, b>=4): 26 total, split 13/13 across passes.
template<int P> struct PairSet;
template<> struct PairSet<0> {
    static constexpr int A[NPR] = {0,1,2,3,4, 0,1,2,3,4,5, 0,1};
    static constexpr int B[NPR] = {4,4,4,4,4, 5,5,5,5,5,5, 6,6};
};
template<> struct PairSet<1> {
    static constexpr int A[NPR] = {2,3,4,5,6, 0,1,2,3,4,5,6,7};
    static constexpr int B[NPR] = {6,6,6,6,6, 7,7,7,7,7,7,7,7};
};

// ---------- DPP wave-64 sum (VALU pipe). Result valid in lane 63. ----------
template<int CTRL>
__device__ __forceinline__ float dpp_add(float x) {
    int v = __builtin_amdgcn_update_dpp(0, __builtin_bit_cast(int, x),
                                        CTRL, 0xf, 0xf, true);
    return x + __builtin_bit_cast(float, v);
}
__device__ __forceinline__ float wave_sum_dpp(float x) {
    x = dpp_add<0x111>(x);   // row_shr:1
    x = dpp_add<0x112>(x);   // row_shr:2
    x = dpp_add<0x114>(x);   // row_shr:4
    x = dpp_add<0x118>(x);   // row_shr:8
    x = dpp_add<0x142>(x);   // row_bcast:15
    x = dpp_add<0x143>(x);   // row_bcast:31 -> lane63 = full wave sum
    return x;
}

// ---------- f32 -> packed (hi f16 in bits 15:0 | lo f16 in bits 31:16) ----------
// rtz rounding via cvt_pkrtz; lo scaled by 1024.
__device__ __forceinline__ uint32 pack_hilo(float v) {
    const uint32 hiu = __builtin_bit_cast(uint32, __builtin_amdgcn_cvt_pkrtz(v, 0.f));
    const float  hf  = (float)__builtin_bit_cast(f16x2, hiu)[0];
    const uint32 lou = __builtin_bit_cast(uint32, __builtin_amdgcn_cvt_pkrtz((v - hf) * 1024.f, 0.f));
    return __builtin_amdgcn_perm(lou, hiu, 0x05040100u);  // b0,b1=hi  b2,b3=lo
}

// ---------- prep: W1,W2 f32 -> hi/lo f16 in MFMA-fragment-contiguous layout ----------
__global__ void prep_kernel(const float* __restrict__ W1, const float* __restrict__ W2,
                            _Float16* __restrict__ ws) {
    const int gid  = blockIdx.x * 256 + threadIdx.x;
    const int layer = gid >> 18;
    const int r     = gid & 262143;
    const int i = r >> 9, j = r & 511;
    const float v = (layer ? W2 : W1)[r];
    const _Float16 hi = (_Float16)v;
    const _Float16 lo = (_Float16)((v - (float)hi) * 1024.f);
    const int mt = i >> 4, m = i & 15, ks = j >> 5, q = (j >> 3) & 3, e = j & 7;
    const int off = (((mt * 16 + ks) * 4 + q) * 16 + m) * 8 + e;
    _Float16* base = ws + (size_t)layer * 524288;
    base[off] = hi;
    base[262144 + off] = lo;
}

// ---------- B-fragment unpack: 8 packed words -> hi/lo f16x8 via v_perm ----------
__device__ __forceinline__ f16x8 unpack_hi(const uint4 d0, const uint4 d1) {
    union { uint32 u[4]; f16x8 v; } uh;
    uh.u[0] = __builtin_amdgcn_perm(d0.y, d0.x, 0x05040100u);
    uh.u[1] = __builtin_amdgcn_perm(d0.w, d0.z, 0x05040100u);
    uh.u[2] = __builtin_amdgcn_perm(d1.y, d1.x, 0x05040100u);
    uh.u[3] = __builtin_amdgcn_perm(d1.w, d1.z, 0x05040100u);
    return uh.v;
}
__device__ __forceinline__ f16x8 unpack_lo(const uint4 d0, const uint4 d1) {
    union { uint32 u[4]; f16x8 v; } ul;
    ul.u[0] = __builtin_amdgcn_perm(d0.y, d0.x, 0x07060302u);
    ul.u[1] = __builtin_amdgcn_perm(d0.w, d0.z, 0x07060302u);
    ul.u[2] = __builtin_amdgcn_perm(d1.y, d1.x, 0x07060302u);
    ul.u[3] = __builtin_amdgcn_perm(d1.w, d1.z, 0x07060302u);
    return ul.v;
}

// ---------- MFMA gemm: D[512, 22] = W * S, result staged back into S (ch-major) ----------
// Bisect step (round 7): single fused K sweep with dual accumulators.
// D = accM + accC/1024, accM = Whi*Shi, accC = Whi*Slo + Wlo*Shi.
// S read ONCE per gemm; sweep-B Whi re-read eliminated. Barrier structure,
// read set, write set identical to the r6-green two-sweep version.
__device__ void gemm_mfma(float* __restrict__ S,
                          const _Float16* __restrict__ Whi,
                          const _Float16* __restrict__ Wlo,
                          int w, int lane)
{
    const int q = lane >> 4, m = lane & 15;
    const int ch0 = m;
    const int ch1 = (16 + m < NCH) ? (16 + m) : (NCH - 1);  // clamp garbage lanes
    f32x4 accM[MIW][2], accC[MIW][2];
    #pragma unroll
    for (int mi = 0; mi < MIW; ++mi) {
        accM[mi][0] = (f32x4){0.f, 0.f, 0.f, 0.f};
        accM[mi][1] = (f32x4){0.f, 0.f, 0.f, 0.f};
        accC[mi][0] = (f32x4){0.f, 0.f, 0.f, 0.f};
        accC[mi][1] = (f32x4){0.f, 0.f, 0.f, 0.f};
    }

    #pragma unroll 1
    for (int ks = 0; ks < 16; ++ks) {
        f16x8 Bhi[2], Blo[2];
        #pragma unroll
        for (int nt = 0; nt < 2; ++nt) {
            const int ch = nt ? ch1 : ch0;
            const uint32* sp = (const uint32*)(S + ch * SSTR + ks * 32 + q * 8);
            const uint4 d0 = *(const uint4*)sp;
            const uint4 d1 = *(const uint4*)(sp + 4);
            Bhi[nt] = unpack_hi(d0, d1);
            Blo[nt] = unpack_lo(d0, d1);
        }
        #pragma unroll
        for (int mi = 0; mi < MIW; ++mi) {
            const size_t fo = ((size_t)((w * MIW + mi) * 16 + ks) * 64 + lane) * 8;
            const f16x8 Ahi = *(const f16x8*)(Whi + fo);
            const f16x8 Alo = *(const f16x8*)(Wlo + fo);
            accM[mi][0] = __builtin_amdgcn_mfma_f32_16x16x32_f16(Ahi, Bhi[0], accM[mi][0], 0, 0, 0);
            accC[mi][0] = __builtin_amdgcn_mfma_f32_16x16x32_f16(Ahi, Blo[0], accC[mi][0], 0, 0, 0);
            accC[mi][0] = __builtin_amdgcn_mfma_f32_16x16x32_f16(Alo, Bhi[0], accC[mi][0], 0, 0, 0);
            accM[mi][1] = __builtin_amdgcn_mfma_f32_16x16x32_f16(Ahi, Bhi[1], accM[mi][1], 0, 0, 0);
            accC[mi][1] = __builtin_amdgcn_mfma_f32_16x16x32_f16(Ahi, Blo[1], accC[mi][1], 0, 0, 0);
            accC[mi][1] = __builtin_amdgcn_mfma_f32_16x16x32_f16(Alo, Bhi[1], accC[mi][1], 0, 0, 0);
        }
    }

    __syncthreads();   // all waves done reading S -> safe to overwrite with D (f32)
    #pragma unroll
    for (int mi = 0; mi < MIW; ++mi) {
        #pragma unroll
        for (int nt = 0; nt < 2; ++nt) {
            const int ch = nt * 16 + m;
            if (ch < NCH) {
                const f32x4 r = accM[mi][nt] + accC[mi][nt] * (1.f / 1024.f);
                const float4 st = {r[0], r[1], r[2], r[3]};
                *(float4*)(S + ch * SSTR + (w * MIW + mi) * 16 + q * 4) = st;
            }
        }
    }
    __syncthreads();
}

__device__ __forceinline__ void readback(float (&vals)[NCH],
                                         const float* __restrict__ b,
                                         const float* __restrict__ S, int tid)
{
    #pragma unroll
    for (int ch = 0; ch < NCH; ++ch) vals[ch] = S[ch * SSTR + tid];   // f32 D, stride-1
    vals[0] += b[tid];
}

// ---------- softplus chain + LN; writes S (packed hi/lo) or accumulates final linear ----------
// Structure identical to the r6-green kernel (reduction stores untouched).
template<int P, bool FINAL>
__device__ void ln_process(float (&vals)[NCH],
        const float* __restrict__ g, const float* __restrict__ be,
        float* __restrict__ S, float* __restrict__ red, float* __restrict__ fin,
        float* __restrict__ drv,
        float* __restrict__ sJ, float* __restrict__ sH,
        int tid, int lane, int w, float w3)
{
    const float pv  = vals[0];
    const float e   = expf(-fabsf(pv));
    const float sig = (pv >= 0.f) ? (1.f / (1.f + e)) : (e / (1.f + e));
    const float h   = fmaxf(pv, 0.f) + log1pf(e);
    const float spp = sig * (1.f - sig);
    #pragma unroll
    for (int t = 0; t < NPR; ++t) {
        const int a = PairSet<P>::A[t], b = PairSet<P>::B[t];
        vals[9+t] = sig * vals[9+t] + spp * vals[1+a] * vals[1+b];
    }
    #pragma unroll
    for (int a = 0; a < 8; ++a) vals[1+a] *= sig;
    vals[0] = h;

    // --- reduction group 1: k = 0..28 (registers die at the red[] store) ---
    {
        float pa[29];
        pa[0] = h;
        pa[1] = h * h;
        #pragma unroll
        for (int a = 0; a < 8; ++a) { pa[2+a] = vals[1+a]; pa[10+a] = h * vals[1+a]; }
        #pragma unroll
        for (int t = 0; t < 11; ++t) pa[18+t] = vals[9+t];
        #pragma unroll
        for (int k = 0; k < 29; ++k) pa[k] = wave_sum_dpp(pa[k]);
        if (lane == 63) {
            #pragma unroll
            for (int k = 0; k < 29; ++k) red[w * NRED + k] = pa[k];
        }
    }
    // --- reduction group 2: k = 29..56 ---
    {
        float pb[28];
        pb[0] = vals[9+11];
        pb[1] = vals[9+12];
        #pragma unroll
        for (int t = 0; t < NPR; ++t) {
            const int a = PairSet<P>::A[t], b = PairSet<P>::B[t];
            pb[2+t]  = vals[1+a] * vals[1+b];
            pb[15+t] = h * vals[9+t];
        }
        #pragma unroll
        for (int k = 0; k < 28; ++k) pb[k] = wave_sum_dpp(pb[k]);
        if (lane == 63) {
            #pragma unroll
            for (int k = 0; k < 28; ++k) red[w * NRED + 29 + k] = pb[k];
        }
    }
    __syncthreads();
    if (tid < NRED) {
        fin[tid] = ((red[tid] + red[NRED + tid]) + (red[2*NRED + tid] + red[3*NRED + tid]))
                 + ((red[4*NRED + tid] + red[5*NRED + tid]) + (red[6*NRED + tid] + red[7*NRED + tid]));
    }
    __syncthreads();

    const float invH = 1.f / HDIM;
    // derived stats -> drv[] : [0]=mean [1]=rs [2..9]=mdot [10..17]=sdot [18..30]=mdd [31..43]=cy
    if (tid < 8) {
        const float mean = fin[0] * invH;
        const float var  = fin[1] * invH - mean * mean;
        const float rs   = rsqrtf(var + LN_EPS);
        if (tid == 0) { drv[0] = mean; drv[1] = rs; }
        const float md = fin[2+tid] * invH;
        drv[2+tid]  = md;
        drv[10+tid] = (fin[10+tid] * invH - mean * md) * rs;
    }
    __syncthreads();
    if (tid < NPR) {
        const float mean = drv[0], rs = drv[1];
        const int a = PairSet<P>::A[tid], b = PairSet<P>::B[tid];
        const float sda = drv[10+a], sdb = drv[10+b];
        const float mdd = fin[18+tid] * invH;
        const float mcc = fin[31+tid] * invH - drv[2+a] * drv[2+b];
        const float mch = fin[44+tid] * invH - mean * mdd;
        const float vdd = 2.f * (mcc + mch);
        const float sdd = (0.5f * vdd - sda * sdb) * rs;
        drv[18+tid] = mdd;
        drv[31+tid] = 2.f * sda * sdb * rs * rs - sdd * rs;
    }
    __syncthreads();

    const float mean = drv[0], rs = drv[1];

    if (!FINAL) {
        const int j = tid;
        const float gi = g[j], bi = be[j];
        const float y = (vals[0] - mean) * rs;
        uint32* Su = (uint32*)S;
        Su[0 * SSTR + j] = pack_hilo(y * gi + bi);
        float cd[8];
        #pragma unroll
        for (int a = 0; a < 8; ++a) {
            cd[a] = vals[1+a] - drv[2+a];
            Su[(1+a) * SSTR + j] = pack_hilo((cd[a] - y * drv[10+a]) * rs * gi);
        }
        #pragma unroll
        for (int t = 0; t < NPR; ++t) {
            const int a = PairSet<P>::A[t], b = PairSet<P>::B[t];
            const float cdd = vals[9+t] - drv[18+t];
            const float ydd = cdd * rs - (cd[a]*drv[10+b] + cd[b]*drv[10+a]) * rs * rs
                              + y * drv[31+t];
            Su[(9+t) * SSTR + j] = pack_hilo(ydd * gi);
        }
    } else {
        float pf[NCH];
        const int j = tid;
        const float gi = g[j], bi = be[j];
        const float y = (vals[0] - mean) * rs;
        pf[0] = w3 * (y * gi + bi);
        float cd[8];
        #pragma unroll
        for (int a = 0; a < 8; ++a) {
            cd[a] = vals[1+a] - drv[2+a];
            pf[1+a] = w3 * ((cd[a] - y * drv[10+a]) * rs * gi);
        }
        #pragma unroll
        for (int t = 0; t < NPR; ++t) {
            const int a = PairSet<P>::A[t], b = PairSet<P>::B[t];
            const float cdd = vals[9+t] - drv[18+t];
            const float ydd = cdd * rs - (cd[a]*drv[10+b] + cd[b]*drv[10+a]) * rs * rs
                              + y * drv[31+t];
            pf[9+t] = w3 * (ydd * gi);
        }
        #pragma unroll
        for (int k = 0; k < NCH; ++k) pf[k] = wave_sum_dpp(pf[k]);
        if (lane == 63) {
            #pragma unroll
            for (int k = 0; k < NCH; ++k) red[w * NRED + k] = pf[k];
        }
        __syncthreads();
        if (tid < NCH) {
            fin[tid] = ((red[tid] + red[NRED + tid]) + (red[2*NRED + tid] + red[3*NRED + tid]))
                     + ((red[4*NRED + tid] + red[5*NRED + tid]) + (red[6*NRED + tid] + red[7*NRED + tid]));
        }
        __syncthreads();
        if (tid == 0) {
            if (P == 0) {
                #pragma unroll
                for (int a = 0; a < 8; ++a) sJ[a] = fin[1 + a];
            }
            #pragma unroll
            for (int t = 0; t < NPR; ++t) sH[P * NPR + t] = fin[9 + t];
        }
    }
}

template<int P>
__device__ void run_pass(int tid, int lane, int w, const float (&q)[8],
        const float* __restrict__ W0, const float* __restrict__ b0,
        const float* __restrict__ g0, const float* __restrict__ be0,
        const float* __restrict__ b1, const float* __restrict__ g1,
        const float* __restrict__ be1,
        const float* __restrict__ b2, const float* __restrict__ g2,
        const float* __restrict__ be2,
        const _Float16* __restrict__ Wf,
        float w3,
        float* S, float* red, float* fin, float* drv, float* sJ, float* sH)
{
    float vals[NCH];

    // ---- layer 0: q(8) -> 512 (no gemm); grads = W0 row, hess = 0
    {
        const float4 wa = *(const float4*)(W0 + tid * 8);
        const float4 wb = *(const float4*)(W0 + tid * 8 + 4);
        vals[0] = b0[tid]
            + wa.x*q[0] + wa.y*q[1] + wa.z*q[2] + wa.w*q[3]
            + wb.x*q[4] + wb.y*q[5] + wb.z*q[6] + wb.w*q[7];
        vals[1] = wa.x; vals[2] = wa.y; vals[3] = wa.z; vals[4] = wa.w;
        vals[5] = wb.x; vals[6] = wb.y; vals[7] = wb.z; vals[8] = wb.w;
        #pragma unroll
        for (int t = 0; t < NPR; ++t) vals[9+t] = 0.f;
    }
    ln_process<P, false>(vals, g0, be0, S, red, fin, drv, sJ, sH, tid, lane, w, w3);
    __syncthreads();

    // ---- layer 1
    gemm_mfma(S, Wf, Wf + 262144, w, lane);
    readback(vals, b1, S, tid);
    ln_process<P, false>(vals, g1, be1, S, red, fin, drv, sJ, sH, tid, lane, w, w3);
    __syncthreads();

    // ---- layer 2
    gemm_mfma(S, Wf + 524288, Wf + 786432, w, lane);
    readback(vals, b2, S, tid);
    ln_process<P, true>(vals, g2, be2, S, red, fin, drv, sJ, sH, tid, lane, w, w3);
    __syncthreads();
}

// Bisect discipline: r6-green + fused-sweep gemm ONLY. Reduction stores,
// sync structure, LDS layout (48KB, no aliasing) byte-identical to round 6.
__global__ __launch_bounds__(TPB, 4)
void lnn_kernel(const float* __restrict__ x,
    const float* __restrict__ W0, const float* __restrict__ b0,
    const float* __restrict__ g0, const float* __restrict__ be0,
    const float* __restrict__ b1, const float* __restrict__ g1,
    const float* __restrict__ be1,
    const float* __restrict__ b2, const float* __restrict__ g2,
    const float* __restrict__ be2,
    const float* __restrict__ W3,
    const _Float16* __restrict__ Wf,
    float* __restrict__ out)
{
    __shared__ __align__(16) float S[NCH * SSTR];   // 45.4 KB: state / D-staging
    __shared__ __align__(16) float red[NW * NRED];
    __shared__ __align__(16) float fin[NRED + 3];
    __shared__ float drv[44];
    __shared__ float sJ[8];
    __shared__ float sH[26];

    const int tid  = threadIdx.x;
    const int lane = tid & 63;
    const int w    = tid >> 6;
    const long sample = blockIdx.x;

    float q[8];
    #pragma unroll
    for (int a = 0; a < 8; ++a) q[a] = x[sample * 8 + a];
    const float w3 = W3[tid];

    run_pass<0>(tid, lane, w, q, W0, b0, g0, be0, b1, g1, be1, b2, g2, be2,
                Wf, w3, S, red, fin, drv, sJ, sH);
    run_pass<1>(tid, lane, w, q, W0, b0, g0, be0, b1, g1, be1, b2, g2, be2,
                Wf, w3, S, red, fin, drv, sJ, sH);

    if (tid == 0) {
        const int off[4] = {0, 5, 11, 18};
        double Hd[26];
        for (int t = 0; t < 26; ++t) Hd[t] = (double)sH[t];
        double r[4];
        for (int k = 0; k < 4; ++k) {
            double s = (double)sJ[k];
            for (int j = 0; j < 4; ++j) s -= Hd[off[k] + j] * (double)q[4 + j];
            r[k] = s;
        }
        double A[4][5];
        for (int jj = 0; jj < 4; ++jj) {
            for (int k = 0; k < 4; ++k) {
                const int lo = (jj < k ? jj : k) + 4;
                const int hi = (jj < k ? k : jj) + 4;
                A[jj][k] = Hd[off[hi - 4] + lo];
            }
            A[jj][4] = r[jj];
        }
        for (int c = 0; c < 4; ++c) {
            int pr = c; double mx = fabs(A[c][c]);
            for (int rr = c + 1; rr < 4; ++rr)
                if (fabs(A[rr][c]) > mx) { mx = fabs(A[rr][c]); pr = rr; }
            if (pr != c)
                for (int cc = c; cc < 5; ++cc) {
                    double t = A[c][cc]; A[c][cc] = A[pr][cc]; A[pr][cc] = t;
                }
            const double pinv = 1.0 / A[c][c];
            for (int rr = 0; rr < 4; ++rr) if (rr != c) {
                const double f = A[rr][c] * pinv;
                for (int cc = c; cc < 5; ++cc) A[rr][cc] -= f * A[c][cc];
            }
        }
        #pragma unroll
        for (int k = 0; k < 4; ++k)
            out[sample * 4 + k] = (float)(A[k][4] / A[k][k]);
    }
}

extern "C" void kernel_launch(void* const* d_in, const int* in_sizes, int n_in,
                              void* d_out, int out_size, void* d_ws, size_t ws_size,
                              hipStream_t stream) {
    const float* x   = (const float*)d_in[0];
    const float* W0  = (const float*)d_in[1];
    const float* b0  = (const float*)d_in[2];
    const float* g0  = (const float*)d_in[3];
    const float* be0 = (const float*)d_in[4];
    const float* W1  = (const float*)d_in[5];
    const float* b1  = (const float*)d_in[6];
    const float* g1  = (const float*)d_in[7];
    const float* be1 = (const float*)d_in[8];
    const float* W2  = (const float*)d_in[9];
    const float* b2  = (const float*)d_in[10];
    const float* g2  = (const float*)d_in[11];
    const float* be2 = (const float*)d_in[12];
    const float* W3  = (const float*)d_in[13];
    float* out = (float*)d_out;

    _Float16* Wf = (_Float16*)d_ws;   // 2 MB: [W1hi|W1lo|W2hi|W2lo] fragment layout
    const int B = in_sizes[0] / 8;    // 16384

    hipLaunchKernelGGL(prep_kernel, dim3(2048), dim3(256), 0, stream, W1, W2, Wf);
    hipLaunchKernelGGL(lnn_kernel, dim3(B), dim3(TPB), 0, stream,
                       x, W0, b0, g0, be0, b1, g1, be1, b2, g2, be2, W3, Wf, out);
}